// Round 15
// baseline (348.945 us; speedup 1.0000x reference)
//
#include <hip/hip_runtime.h>
#include <hip/hip_bf16.h>

#define D_HID 2048
#define F_EXP 1408
#define E_NUM 8
#define FS_SH 2816
#define T_TOK 2048

// bf16 element offsets inside the converted-weight block wb
#define O_WSG 0
#define O_WSU 5767168
#define O_WG  11534336
#define O_WU  34603008
#define O_WSD 57671680
#define O_WD  63438848
#define W_TOT 86507520

#define MAXT 24          // routed 256-row tiles
#define GU_SH_BLK 176
#define GU_GEMM   440    // = 8*55
#define GU_CONV   184
#define DN_SH_BLK 64     // shared down: 8 nt(256) * 8 mt
#define DN_GRID   256    // 64 + 24*8  (= 8*32) -> exactly one scheduling round
#define RT_BLK    512
#define WC_BLK    1408

typedef __attribute__((ext_vector_type(8))) short bf16x8;
typedef __attribute__((ext_vector_type(4))) float f32x4;
typedef __attribute__((ext_vector_type(4))) unsigned short u16x4;

#define AS1 __attribute__((address_space(1)))
#define AS3 __attribute__((address_space(3)))

__device__ __forceinline__ unsigned short f2bf(float f){
  unsigned u = __float_as_uint(f);
  u += 0x7fffu + ((u >> 16) & 1u);          // RNE
  return (unsigned short)(u >> 16);
}
__device__ __forceinline__ float bf2f(unsigned short h){
  return __uint_as_float(((unsigned)h) << 16);
}

// ---------------- prep: router (+x->bf16) and gate/up weight fp32->bf16 ----------------
__global__ __launch_bounds__(256) void prep_kernel(
    const float* __restrict__ x,  const float* __restrict__ Wr,
    const float* __restrict__ Wsg, const float* __restrict__ Wsu,
    const float* __restrict__ Wg,  const float* __restrict__ Wu,
    unsigned short* __restrict__ xb, unsigned short* __restrict__ wb,
    int* __restrict__ topk_e, float* __restrict__ topk_w)
{
  const int b = blockIdx.x;
  if (b >= RT_BLK){
    // converter role: 16 floats per thread per iter (fatter chains, better MLP)
    const int cb = b - RT_BLK;
    const long nchunk = (long)O_WSD / 16;   // 3,604,480
    for (long i = (long)cb*256 + threadIdx.x; i < nchunk; i += (long)WC_BLK*256){
      const long e0 = i * 16;
      const float* src; long lo;
      if      (e0 < (long)O_WSU){ src = Wsg; lo = e0; }
      else if (e0 < (long)O_WG ){ src = Wsu; lo = e0 - O_WSU; }
      else if (e0 < (long)O_WU ){ src = Wg;  lo = e0 - O_WG;  }
      else                      { src = Wu;  lo = e0 - O_WU;  }
      const float4 v0 = ((const float4*)(src + lo))[0];
      const float4 v1 = ((const float4*)(src + lo))[1];
      const float4 v2 = ((const float4*)(src + lo))[2];
      const float4 v3 = ((const float4*)(src + lo))[3];
      u16x4 h0, h1, h2, h3;
      h0[0]=f2bf(v0.x); h0[1]=f2bf(v0.y); h0[2]=f2bf(v0.z); h0[3]=f2bf(v0.w);
      h1[0]=f2bf(v1.x); h1[1]=f2bf(v1.y); h1[2]=f2bf(v1.z); h1[3]=f2bf(v1.w);
      h2[0]=f2bf(v2.x); h2[1]=f2bf(v2.y); h2[2]=f2bf(v2.z); h2[3]=f2bf(v2.w);
      h3[0]=f2bf(v3.x); h3[1]=f2bf(v3.y); h3[2]=f2bf(v3.z); h3[3]=f2bf(v3.w);
      ((u16x4*)(wb + e0))[0] = h0;
      ((u16x4*)(wb + e0))[1] = h1;
      ((u16x4*)(wb + e0))[2] = h2;
      ((u16x4*)(wb + e0))[3] = h3;
    }
    return;
  }
  const int lane = threadIdx.x & 63;
  const int t = b*4 + (threadIdx.x >> 6);
  const float* xt = x + (size_t)t * D_HID;
  unsigned short* xbt = xb + (size_t)t * D_HID;
  float acc[E_NUM];
  #pragma unroll
  for (int e=0;e<E_NUM;e++) acc[e]=0.f;
  #pragma unroll
  for (int j=0;j<8;j++){
    const int d = j*256 + lane*4;
    const float4 v = *(const float4*)(xt + d);
    u16x4 h;
    h[0]=f2bf(v.x); h[1]=f2bf(v.y); h[2]=f2bf(v.z); h[3]=f2bf(v.w);
    *(u16x4*)(xbt + d) = h;
    #pragma unroll
    for (int e=0;e<E_NUM;e++){
      const float4 w = *(const float4*)(Wr + e*D_HID + d);
      acc[e] += v.x*w.x + v.y*w.y + v.z*w.z + v.w*w.w;
    }
  }
  #pragma unroll
  for (int e=0;e<E_NUM;e++){
    #pragma unroll
    for (int off=32; off>0; off>>=1) acc[e] += __shfl_xor(acc[e], off);
  }
  if (lane==0){
    float m = acc[0];
    #pragma unroll
    for (int e=1;e<E_NUM;e++) m = fmaxf(m, acc[e]);
    float p[E_NUM]; float s = 0.f;
    #pragma unroll
    for (int e=0;e<E_NUM;e++){ p[e] = expf(acc[e]-m); s += p[e]; }
    const float inv = 1.f/s;
    int i0=0; float b0=p[0];
    #pragma unroll
    for (int e=1;e<E_NUM;e++) if (p[e] > b0){ b0=p[e]; i0=e; }
    int i1=-1; float b1=-1.f;
    #pragma unroll
    for (int e=0;e<E_NUM;e++) if (e!=i0 && p[e] > b1){ b1=p[e]; i1=e; }
    topk_e[t*2+0]=i0; topk_e[t*2+1]=i1;
    topk_w[t*2+0]=b0*inv; topk_w[t*2+1]=b1*inv;
  }
}

// ---------------- deterministic expert-grouped list build + 256-row tile records --------
__global__ __launch_bounds__(1024) void build_lists_kernel(
    const int* __restrict__ topk_e, const float* __restrict__ topk_w,
    int* __restrict__ cnt, int* __restrict__ offs,
    int* __restrict__ assign_token, float* __restrict__ assign_w,
    int* __restrict__ token_slot,
    int* __restrict__ tile_rowbase, int* __restrict__ tile_e,
    int* __restrict__ tile_valid, int* __restrict__ n_rt)
{
  const int tid  = threadIdx.x;
  const int lane = tid & 63;
  const int wv   = tid >> 6;                 // 16 waves
  __shared__ int wsum[E_NUM][16];
  __shared__ int tot_s[E_NUM];
  __shared__ int offs_s[E_NUM];

  int   e_loc[4];
  float w_loc[4];
  #pragma unroll
  for (int j=0;j<4;j++){ e_loc[j]=topk_e[tid*4+j]; w_loc[j]=topk_w[tid*4+j]; }

  int c[E_NUM];
  #pragma unroll
  for (int e=0;e<E_NUM;e++){
    int s = 0;
    #pragma unroll
    for (int j=0;j<4;j++) s += (e_loc[j]==e) ? 1 : 0;
    c[e] = s;
  }
  int pre[E_NUM];
  #pragma unroll
  for (int e=0;e<E_NUM;e++){
    int v = c[e];
    #pragma unroll
    for (int off=1; off<64; off<<=1){
      int t = __shfl_up(v, off);
      if (lane >= off) v += t;
    }
    if (lane==63) wsum[e][wv] = v;
    pre[e] = v - c[e];
  }
  __syncthreads();
  if (tid < E_NUM){
    int s = 0;
    #pragma unroll
    for (int w=0; w<16; w++){ int t = wsum[tid][w]; wsum[tid][w] = s; s += t; }
    tot_s[tid] = s;
    cnt[tid]   = s;
  }
  __syncthreads();
  if (tid == 0){
    int s = 0;
    #pragma unroll
    for (int e=0;e<E_NUM;e++){ offs_s[e] = s; offs[e] = s; s += tot_s[e]; }
    int ntl = 0;
    for (int e=0;e<E_NUM;e++){
      for (int r=0; r<tot_s[e]; r+=256){
        tile_rowbase[ntl] = offs_s[e] + r;
        tile_e[ntl]       = e;
        int v = tot_s[e] - r; if (v > 256) v = 256;
        tile_valid[ntl]   = v;
        ntl++;
      }
    }
    n_rt[0] = ntl;
    for (int i=ntl;i<MAXT;i++){ tile_rowbase[i]=0; tile_e[i]=0; tile_valid[i]=0; }
  }
  __syncthreads();
  int local[E_NUM];
  #pragma unroll
  for (int e=0;e<E_NUM;e++) local[e]=0;
  #pragma unroll
  for (int j=0;j<4;j++){
    const int e = e_loc[j];
    int pos = 0;
    #pragma unroll
    for (int ee=0; ee<E_NUM; ee++)
      if (e == ee) pos = offs_s[ee] + wsum[ee][wv] + pre[ee] + local[ee];
    #pragma unroll
    for (int ee=0; ee<E_NUM; ee++) local[ee] += (e == ee) ? 1 : 0;
    const int entry = tid*4 + j;
    assign_token[pos] = entry >> 1;
    assign_w[pos]     = w_loc[j];
    token_slot[entry] = pos;
  }
}

// ========== gate+up GEMM: BK=32, 2-buf (64 KB LDS -> 2 blocks/CU), r5 counted loop =====
__global__ __launch_bounds__(512,2) void gateup_fused(
    const unsigned short* __restrict__ xb,
    unsigned short* __restrict__ wb,
    const float* __restrict__ Wsd_f, const float* __restrict__ Wd_f,
    unsigned short* __restrict__ h_shared,
    unsigned short* __restrict__ h_routed,
    const int* __restrict__ tile_rowbase, const int* __restrict__ tile_e,
    const int* __restrict__ tile_valid, const int* __restrict__ n_rt,
    const int* __restrict__ assign_token)
{
  __shared__ __align__(16) char As[2][256*64];   // 32 KB
  __shared__ __align__(16) char Bg[2][128*64];   // 16 KB
  __shared__ __align__(16) char Bu[2][128*64];   // 16 KB

  const int tid  = threadIdx.x;
  const int braw = blockIdx.x;

  if (braw >= GU_GEMM){
    const int cb = braw - GU_GEMM;                  // 0..183
    const long nchunk = (long)(W_TOT - O_WSD) / 8;  // 3,604,480
    for (long i = (long)cb*512 + tid; i < nchunk; i += (long)GU_CONV*512){
      const long e0 = (long)O_WSD + i * 8;
      const float* src; long lo;
      if (e0 < (long)O_WD){ src = Wsd_f; lo = e0 - O_WSD; } else { src = Wd_f; lo = e0 - O_WD; }
      const float4 va = ((const float4*)(src + lo))[0];
      const float4 vb = ((const float4*)(src + lo))[1];
      u16x4 h0, h1;
      h0[0]=f2bf(va.x); h0[1]=f2bf(va.y); h0[2]=f2bf(va.z); h0[3]=f2bf(va.w);
      h1[0]=f2bf(vb.x); h1[1]=f2bf(vb.y); h1[2]=f2bf(vb.z); h1[3]=f2bf(vb.w);
      ((u16x4*)(wb + e0))[0] = h0;
      ((u16x4*)(wb + e0))[1] = h1;
    }
    return;
  }

  const int b = (braw % 8) * (GU_GEMM/8) + braw / 8;   // XCD swizzle (440 = 8*55)

  const int lane = tid & 63;
  const int wave = tid >> 6;       // 0..7
  const int wr = wave >> 1;        // 0..3
  const int wc = wave & 1;         // 0..1

  int nt, rowbase, valid, gather;
  const unsigned short *wg_base, *wu_base;
  unsigned short* H; int N;
  if (b < GU_SH_BLK){
    nt = b >> 3; const int mtile = b & 7;
    rowbase = mtile*256; valid = 256; gather = 0;
    wg_base = wb + O_WSG + (size_t)(nt*128) * D_HID;
    wu_base = wb + O_WSU + (size_t)(nt*128) * D_HID;
    H = h_shared; N = FS_SH;
  } else {
    const int rb = b - GU_SH_BLK;
    const int tile = rb % MAXT;
    nt = rb / MAXT;                              // 0..10
    if (tile >= n_rt[0]) return;
    rowbase = tile_rowbase[tile];
    valid   = tile_valid[tile];
    const int e = tile_e[tile];
    gather = 1;
    wg_base = wb + O_WG + ((size_t)e*F_EXP + nt*128) * D_HID;
    wu_base = wb + O_WU + ((size_t)e*F_EXP + nt*128) * D_HID;
    H = h_routed; N = F_EXP;
  }

  f32x4 accg[4][4], accu[4][4];
  const f32x4 z = {0.f,0.f,0.f,0.f};
  #pragma unroll
  for (int m=0;m<4;m++)
    #pragma unroll
    for (int n=0;n<4;n++){ accg[m][n]=z; accu[m][n]=z; }

  const char* asrc[2];
  const int rowmax = rowbase + valid - 1;
  #pragma unroll
  for (int p=0;p<2;p++){
    const int c = p*512 + tid;
    const int row = c >> 2, slot = c & 3;
    const int col16 = slot ^ ((row>>1)&3);
    int idx = rowbase + row;
    if (idx > rowmax) idx = rowmax;
    const size_t grow = gather ? (size_t)assign_token[idx] : (size_t)idx;
    asrc[p] = (const char*)(xb + grow * (size_t)D_HID) + (col16<<4);
  }
  const int brw = tid >> 2, bsl = tid & 3;
  const int bcol16 = bsl ^ ((brw>>1)&3);
  const char* gsrc = (const char*)(wg_base + (size_t)brw * D_HID) + (bcol16<<4);
  const char* usrc = (const char*)(wu_base + (size_t)brw * D_HID) + (bcol16<<4);

  auto stage = [&](int bi, int kt){     // 4 loads per thread
    #pragma unroll
    for (int p=0;p<2;p++)
      __builtin_amdgcn_global_load_lds(
        (const AS1 void*)(asrc[p] + kt*64),
        (AS3 void*)(&As[bi][(p*512 + tid)*16]), 16, 0, 0);
    __builtin_amdgcn_global_load_lds(
        (const AS1 void*)(gsrc + kt*64),
        (AS3 void*)(&Bg[bi][tid*16]), 16, 0, 0);
    __builtin_amdgcn_global_load_lds(
        (const AS1 void*)(usrc + kt*64),
        (AS3 void*)(&Bu[bi][tid*16]), 16, 0, 0);
  };

  const int arow0 = wr*64 + (lane & 15);
  const int brow0 = wc*64 + (lane & 15);
  const int sread = (lane >> 4) << 4;

  const int nK = D_HID / 32;   // 64
  stage(0, 0);
  int cur = 0;
  #pragma unroll 1
  for (int kt = 0; kt < nK; ++kt){
    if (kt + 1 < nK){
      stage(cur^1, kt+1);      // 8 outstanding; wait current tile's 4 (T4: next stays in flight)
      asm volatile("s_waitcnt vmcnt(4)\n\ts_barrier" ::: "memory");
    } else {
      asm volatile("s_waitcnt vmcnt(0)\n\ts_barrier" ::: "memory");
    }
    bf16x8 a[4], bgr[4], bur[4];
    #pragma unroll
    for (int m=0;m<4;m++){
      const int r = arow0 + m*16;
      a[m] = *(const bf16x8*)(&As[cur][r*64 + (sread ^ (((r>>1)&3)<<4))]);
    }
    #pragma unroll
    for (int n=0;n<4;n++){
      const int r = brow0 + n*16;
      const int ofs = r*64 + (sread ^ (((r>>1)&3)<<4));
      bgr[n] = *(const bf16x8*)(&Bg[cur][ofs]);
      bur[n] = *(const bf16x8*)(&Bu[cur][ofs]);
    }
    #pragma unroll
    for (int m=0;m<4;m++)
      #pragma unroll
      for (int n=0;n<4;n++){
        accg[m][n] = __builtin_amdgcn_mfma_f32_16x16x32_bf16(a[m], bgr[n], accg[m][n], 0,0,0);
        accu[m][n] = __builtin_amdgcn_mfma_f32_16x16x32_bf16(a[m], bur[n], accu[m][n], 0,0,0);
      }
    asm volatile("s_barrier" ::: "memory");   // all reads of cur done before next re-stage
    cur ^= 1;
  }

  const int colbase = nt*128 + wc*64;
  #pragma unroll
  for (int m=0;m<4;m++){
    #pragma unroll
    for (int r=0;r<4;r++){
      const int rr = wr*64 + m*16 + ((lane >> 4) << 2) + r;
      if (rr < valid){
        unsigned short* orow = H + (size_t)(rowbase + rr) * N;
        #pragma unroll
        for (int n=0;n<4;n++){
          const int col = colbase + n*16 + (lane & 15);
          const float g2 = accg[m][n][r];
          const float u = accu[m][n][r];
          const float h = (g2 / (1.f + __expf(-g2))) * u;
          orow[col] = f2bf(h);
        }
      }
    }
  }
}

// ====== down GEMM: BM=256, BN=256, BK=32, 4-buf, 3-deep; grid = exactly 256 blocks ======
__global__ __launch_bounds__(512,2) void down_fused(
    const unsigned short* __restrict__ h_shared,
    const unsigned short* __restrict__ h_routed,
    const unsigned short* __restrict__ wb,
    float* __restrict__ out, unsigned short* __restrict__ y_routed,
    const int* __restrict__ tile_rowbase, const int* __restrict__ tile_e,
    const int* __restrict__ tile_valid, const int* __restrict__ n_rt)
{
  __shared__ __align__(16) char As[4][256*64];   // 64 KB
  __shared__ __align__(16) char Bs[4][256*64];   // 64 KB

  const int tid  = threadIdx.x;
  const int braw = blockIdx.x;
  const int b = (braw % 8) * (DN_GRID/8) + braw / 8;   // XCD swizzle (256 = 8*32)
  const int lane = tid & 63;
  const int wave = tid >> 6;
  const int wr = wave >> 1, wc = wave & 1;

  int nt, rowbase, valid, routed, K;
  const unsigned short *A, *w_base;
  if (b < DN_SH_BLK){
    nt = b >> 3; const int mtile = b & 7;
    rowbase = mtile*256; valid = 256; routed = 0;
    A = h_shared; K = FS_SH;
    w_base = wb + O_WSD + (size_t)(nt*256) * FS_SH;
  } else {
    const int rb = b - DN_SH_BLK;
    const int tile = rb % MAXT;
    nt = rb / MAXT;                             // 0..7
    if (tile >= n_rt[0]) return;
    rowbase = tile_rowbase[tile];
    valid   = tile_valid[tile];
    const int e = tile_e[tile];
    routed = 1;
    A = h_routed; K = F_EXP;
    w_base = wb + O_WD + ((size_t)e*D_HID + nt*256) * F_EXP;
  }
  const size_t K2 = (size_t)K * 2;

  f32x4 acc[4][8];
  const f32x4 z = {0.f,0.f,0.f,0.f};
  #pragma unroll
  for (int m=0;m<4;m++)
    #pragma unroll
    for (int n=0;n<8;n++) acc[m][n]=z;

  const char* asrc[2];
  const int rowmax = rowbase + valid - 1;
  #pragma unroll
  for (int p=0;p<2;p++){
    const int c = p*512 + tid;
    const int row = c >> 2, slot = c & 3;
    const int col16 = slot ^ ((row>>1)&3);
    int idx = rowbase + row;
    if (idx > rowmax) idx = rowmax;
    asrc[p] = (const char*)A + (size_t)idx * K2 + (col16<<4);
  }
  const char* bsrc[2];
  #pragma unroll
  for (int p=0;p<2;p++){
    const int c = p*512 + tid;
    const int row = c >> 2, slot = c & 3;
    const int col16 = slot ^ ((row>>1)&3);
    bsrc[p] = (const char*)(w_base + (size_t)row * K) + (col16<<4);
  }

  auto stage = [&](int bi, int kt){     // 4 loads per thread
    #pragma unroll
    for (int p=0;p<2;p++)
      __builtin_amdgcn_global_load_lds(
        (const AS1 void*)(asrc[p] + kt*64),
        (AS3 void*)(&As[bi][(p*512 + tid)*16]), 16, 0, 0);
    #pragma unroll
    for (int p=0;p<2;p++)
      __builtin_amdgcn_global_load_lds(
        (const AS1 void*)(bsrc[p] + kt*64),
        (AS3 void*)(&Bs[bi][(p*512 + tid)*16]), 16, 0, 0);
  };

  const int nK = K / 32;       // 88 or 44
  stage(0,0); stage(1,1); stage(2,2);   // 12 outstanding

  const int arow0 = wr*64 + (lane & 15);
  const int brow0 = wc*128 + (lane & 15);
  const int sread = (lane >> 4) << 4;

  #pragma unroll 1
  for (int kt = 0; kt < nK; ++kt){
    if (kt < nK-2)       asm volatile("s_waitcnt vmcnt(8)\n\ts_barrier" ::: "memory");
    else if (kt == nK-2) asm volatile("s_waitcnt vmcnt(4)\n\ts_barrier" ::: "memory");
    else                 asm volatile("s_waitcnt vmcnt(0)\n\ts_barrier" ::: "memory");
    const int bi = kt & 3;
    bf16x8 a[4], bb[8];
    #pragma unroll
    for (int m=0;m<4;m++){
      const int r = arow0 + m*16;
      a[m] = *(const bf16x8*)(&As[bi][r*64 + (sread ^ (((r>>1)&3)<<4))]);
    }
    #pragma unroll
    for (int n=0;n<8;n++){
      const int r = brow0 + n*16;
      bb[n] = *(const bf16x8*)(&Bs[bi][r*64 + (sread ^ (((r>>1)&3)<<4))]);
    }
    if (kt + 3 < nK) stage((kt+3)&3, kt+3);
    #pragma unroll
    for (int m=0;m<4;m++)
      #pragma unroll
      for (int n=0;n<8;n++)
        acc[m][n] = __builtin_amdgcn_mfma_f32_16x16x32_bf16(a[m], bb[n], acc[m][n], 0,0,0);
  }

  const int colbase = nt*256 + wc*128;
  #pragma unroll
  for (int m=0;m<4;m++){
    #pragma unroll
    for (int r=0;r<4;r++){
      const int rr = wr*64 + m*16 + ((lane >> 4) << 2) + r;
      if (rr < valid){
        if (routed){
          unsigned short* orow = y_routed + (size_t)(rowbase + rr) * D_HID;
          #pragma unroll
          for (int n=0;n<8;n++){
            const int col = colbase + n*16 + (lane & 15);
            orow[col] = f2bf(acc[m][n][r]);
          }
        } else {
          float* orow = out + (size_t)(rowbase + rr) * D_HID;
          #pragma unroll
          for (int n=0;n<8;n++){
            const int col = colbase + n*16 + (lane & 15);
            orow[col] = acc[m][n][r];
          }
        }
      }
    }
  }
}

// ---------------- combine: out += w0*y[slot0] + w1*y[slot1]  (y is bf16, unweighted) ----
__global__ void combine_kernel(float* __restrict__ out, const unsigned short* __restrict__ y,
                               const int* __restrict__ token_slot,
                               const float* __restrict__ topk_w){
  const int i  = blockIdx.x * blockDim.x + threadIdx.x;   // float4 index into out
  const int t  = i >> 9;
  const int r4 = i & 511;
  const int s0 = token_slot[t*2+0];
  const int s1 = token_slot[t*2+1];
  const float w0 = topk_w[t*2+0];
  const float w1 = topk_w[t*2+1];
  const u16x4 a = ((const u16x4*)(y + (size_t)s0 * D_HID))[r4];
  const u16x4 bq = ((const u16x4*)(y + (size_t)s1 * D_HID))[r4];
  float4 o = ((float4*)out)[i];
  o.x += w0*bf2f(a[0]) + w1*bf2f(bq[0]);
  o.y += w0*bf2f(a[1]) + w1*bf2f(bq[1]);
  o.z += w0*bf2f(a[2]) + w1*bf2f(bq[2]);
  o.w += w0*bf2f(a[3]) + w1*bf2f(bq[3]);
  ((float4*)out)[i] = o;
}

extern "C" void kernel_launch(void* const* d_in, const int* in_sizes, int n_in,
                              void* d_out, int out_size, void* d_ws, size_t ws_size,
                              hipStream_t stream){
  const float* x   = (const float*)d_in[0];
  const float* Wr  = (const float*)d_in[1];
  const float* Wg  = (const float*)d_in[2];
  const float* Wu  = (const float*)d_in[3];
  const float* Wd  = (const float*)d_in[4];
  const float* Wsg = (const float*)d_in[5];
  const float* Wsu = (const float*)d_in[6];
  const float* Wsd = (const float*)d_in[7];
  float* out = (float*)d_out;
  (void)in_sizes; (void)n_in; (void)out_size; (void)ws_size;

  char* ws = (char*)d_ws;
  size_t off = 0;
  auto alloc = [&](size_t bytes)->char*{
    char* p = ws + off; off += (bytes + 255) & ~(size_t)255; return p;
  };

  unsigned short* wb       = (unsigned short*)alloc((size_t)W_TOT * 2);
  unsigned short* xb       = (unsigned short*)alloc((size_t)T_TOK * D_HID * 2);
  unsigned short* h_shared = (unsigned short*)alloc((size_t)T_TOK * FS_SH * 2);
  unsigned short* h_routed = (unsigned short*)alloc((size_t)T_TOK * 2 * F_EXP * 2);
  unsigned short* y_routed = (unsigned short*)alloc((size_t)T_TOK * 2 * D_HID * 2);
  int*   topk_e       = (int*)alloc(T_TOK*2*sizeof(int));
  float* topk_w       = (float*)alloc(T_TOK*2*sizeof(float));
  int*   cnt          = (int*)alloc(E_NUM*sizeof(int));
  int*   offs         = (int*)alloc(E_NUM*sizeof(int));
  int*   assign_token = (int*)alloc(T_TOK*2*sizeof(int));
  float* assign_w     = (float*)alloc(T_TOK*2*sizeof(float));
  int*   token_slot   = (int*)alloc(T_TOK*2*sizeof(int));
  int*   tile_rowbase = (int*)alloc(MAXT*sizeof(int));
  int*   tile_e       = (int*)alloc(MAXT*sizeof(int));
  int*   tile_valid   = (int*)alloc(MAXT*sizeof(int));
  int*   n_rt         = (int*)alloc(sizeof(int));

  prep_kernel<<<RT_BLK + WC_BLK, 256, 0, stream>>>(
      x, Wr, Wsg, Wsu, Wg, Wu, xb, wb, topk_e, topk_w);
  build_lists_kernel<<<1, 1024, 0, stream>>>(topk_e, topk_w, cnt, offs,
      assign_token, assign_w, token_slot, tile_rowbase, tile_e, tile_valid, n_rt);

  gateup_fused<<<GU_GEMM + GU_CONV, 512, 0, stream>>>(
      xb, wb, Wsd, Wd, h_shared, h_routed, tile_rowbase, tile_e, tile_valid, n_rt, assign_token);
  down_fused<<<DN_GRID, 512, 0, stream>>>(
      h_shared, h_routed, wb, out, y_routed, tile_rowbase, tile_e, tile_valid, n_rt);

  combine_kernel<<<(T_TOK*D_HID/4)/256, 256, 0, stream>>>(out, y_routed, token_slot, topk_w);
}

// Round 16
// 335.849 us; speedup vs baseline: 1.0390x; 1.0390x over previous
//
#include <hip/hip_runtime.h>
#include <hip/hip_bf16.h>

#define D_HID 2048
#define F_EXP 1408
#define E_NUM 8
#define FS_SH 2816
#define T_TOK 2048

// bf16 element offsets inside the converted-weight block wb
#define O_WSG 0
#define O_WSU 5767168
#define O_WG  11534336
#define O_WU  34603008
#define O_WSD 57671680
#define O_WD  63438848
#define W_TOT 86507520

#define MAXT 24          // routed 256-row tiles
#define GU_SH_TILE 176   // shared gateup tiles: 22 nt * 8 mt
#define GU_GRID   256    // persistent blocks (1/CU)
#define GU_CONVCH 256    // down-weight conversion chunks interleaved into the queue
#define DN_SH_BLK 64     // shared down: 8 nt(256) * 8 mt
#define DN_GRID   256    // 64 + 24*8  (= 8*32) -> exactly one scheduling round
#define RT_BLK    512
#define WC_BLK    1408

typedef __attribute__((ext_vector_type(8))) short bf16x8;
typedef __attribute__((ext_vector_type(4))) float f32x4;
typedef __attribute__((ext_vector_type(4))) unsigned short u16x4;

#define AS1 __attribute__((address_space(1)))
#define AS3 __attribute__((address_space(3)))

__device__ __forceinline__ unsigned short f2bf(float f){
  unsigned u = __float_as_uint(f);
  u += 0x7fffu + ((u >> 16) & 1u);          // RNE
  return (unsigned short)(u >> 16);
}
__device__ __forceinline__ float bf2f(unsigned short h){
  return __uint_as_float(((unsigned)h) << 16);
}

// ---------------- prep: router (+x->bf16) and gate/up weight fp32->bf16 ----------------
__global__ __launch_bounds__(256) void prep_kernel(
    const float* __restrict__ x,  const float* __restrict__ Wr,
    const float* __restrict__ Wsg, const float* __restrict__ Wsu,
    const float* __restrict__ Wg,  const float* __restrict__ Wu,
    unsigned short* __restrict__ xb, unsigned short* __restrict__ wb,
    int* __restrict__ topk_e, float* __restrict__ topk_w)
{
  const int b = blockIdx.x;
  if (b >= RT_BLK){
    const int cb = b - RT_BLK;
    const long nchunk = (long)O_WSD / 8;    // 7,208,960
    for (long i = (long)cb*256 + threadIdx.x; i < nchunk; i += (long)WC_BLK*256){
      const long e0 = i * 8;
      const float* src; long lo;
      if      (e0 < (long)O_WSU){ src = Wsg; lo = e0; }
      else if (e0 < (long)O_WG ){ src = Wsu; lo = e0 - O_WSU; }
      else if (e0 < (long)O_WU ){ src = Wg;  lo = e0 - O_WG;  }
      else                      { src = Wu;  lo = e0 - O_WU;  }
      const float4 va = ((const float4*)(src + lo))[0];
      const float4 vb = ((const float4*)(src + lo))[1];
      u16x4 h0, h1;
      h0[0]=f2bf(va.x); h0[1]=f2bf(va.y); h0[2]=f2bf(va.z); h0[3]=f2bf(va.w);
      h1[0]=f2bf(vb.x); h1[1]=f2bf(vb.y); h1[2]=f2bf(vb.z); h1[3]=f2bf(vb.w);
      ((u16x4*)(wb + e0))[0] = h0;
      ((u16x4*)(wb + e0))[1] = h1;
    }
    return;
  }
  const int lane = threadIdx.x & 63;
  const int t = b*4 + (threadIdx.x >> 6);
  const float* xt = x + (size_t)t * D_HID;
  unsigned short* xbt = xb + (size_t)t * D_HID;
  float acc[E_NUM];
  #pragma unroll
  for (int e=0;e<E_NUM;e++) acc[e]=0.f;
  #pragma unroll
  for (int j=0;j<8;j++){
    const int d = j*256 + lane*4;
    const float4 v = *(const float4*)(xt + d);
    u16x4 h;
    h[0]=f2bf(v.x); h[1]=f2bf(v.y); h[2]=f2bf(v.z); h[3]=f2bf(v.w);
    *(u16x4*)(xbt + d) = h;
    #pragma unroll
    for (int e=0;e<E_NUM;e++){
      const float4 w = *(const float4*)(Wr + e*D_HID + d);
      acc[e] += v.x*w.x + v.y*w.y + v.z*w.z + v.w*w.w;
    }
  }
  #pragma unroll
  for (int e=0;e<E_NUM;e++){
    #pragma unroll
    for (int off=32; off>0; off>>=1) acc[e] += __shfl_xor(acc[e], off);
  }
  if (lane==0){
    float m = acc[0];
    #pragma unroll
    for (int e=1;e<E_NUM;e++) m = fmaxf(m, acc[e]);
    float p[E_NUM]; float s = 0.f;
    #pragma unroll
    for (int e=0;e<E_NUM;e++){ p[e] = expf(acc[e]-m); s += p[e]; }
    const float inv = 1.f/s;
    int i0=0; float b0=p[0];
    #pragma unroll
    for (int e=1;e<E_NUM;e++) if (p[e] > b0){ b0=p[e]; i0=e; }
    int i1=-1; float b1=-1.f;
    #pragma unroll
    for (int e=0;e<E_NUM;e++) if (e!=i0 && p[e] > b1){ b1=p[e]; i1=e; }
    topk_e[t*2+0]=i0; topk_e[t*2+1]=i1;
    topk_w[t*2+0]=b0*inv; topk_w[t*2+1]=b1*inv;
  }
}

// ---------------- deterministic expert-grouped list build + 256-row tile records --------
__global__ __launch_bounds__(1024) void build_lists_kernel(
    const int* __restrict__ topk_e, const float* __restrict__ topk_w,
    int* __restrict__ cnt, int* __restrict__ offs,
    int* __restrict__ assign_token, float* __restrict__ assign_w,
    int* __restrict__ token_slot,
    int* __restrict__ tile_rowbase, int* __restrict__ tile_e,
    int* __restrict__ tile_valid, int* __restrict__ n_rt,
    int* __restrict__ work_ctr)
{
  const int tid  = threadIdx.x;
  const int lane = tid & 63;
  const int wv   = tid >> 6;                 // 16 waves
  __shared__ int wsum[E_NUM][16];
  __shared__ int tot_s[E_NUM];
  __shared__ int offs_s[E_NUM];

  int   e_loc[4];
  float w_loc[4];
  #pragma unroll
  for (int j=0;j<4;j++){ e_loc[j]=topk_e[tid*4+j]; w_loc[j]=topk_w[tid*4+j]; }

  int c[E_NUM];
  #pragma unroll
  for (int e=0;e<E_NUM;e++){
    int s = 0;
    #pragma unroll
    for (int j=0;j<4;j++) s += (e_loc[j]==e) ? 1 : 0;
    c[e] = s;
  }
  int pre[E_NUM];
  #pragma unroll
  for (int e=0;e<E_NUM;e++){
    int v = c[e];
    #pragma unroll
    for (int off=1; off<64; off<<=1){
      int t = __shfl_up(v, off);
      if (lane >= off) v += t;
    }
    if (lane==63) wsum[e][wv] = v;
    pre[e] = v - c[e];
  }
  __syncthreads();
  if (tid < E_NUM){
    int s = 0;
    #pragma unroll
    for (int w=0; w<16; w++){ int t = wsum[tid][w]; wsum[tid][w] = s; s += t; }
    tot_s[tid] = s;
    cnt[tid]   = s;
  }
  __syncthreads();
  if (tid == 0){
    int s = 0;
    #pragma unroll
    for (int e=0;e<E_NUM;e++){ offs_s[e] = s; offs[e] = s; s += tot_s[e]; }
    int ntl = 0;
    for (int e=0;e<E_NUM;e++){
      for (int r=0; r<tot_s[e]; r+=256){
        tile_rowbase[ntl] = offs_s[e] + r;
        tile_e[ntl]       = e;
        int v = tot_s[e] - r; if (v > 256) v = 256;
        tile_valid[ntl]   = v;
        ntl++;
      }
    }
    n_rt[0] = ntl;
    for (int i=ntl;i<MAXT;i++){ tile_rowbase[i]=0; tile_e[i]=0; tile_valid[i]=0; }
    work_ctr[0] = 0;
  }
  __syncthreads();
  int local[E_NUM];
  #pragma unroll
  for (int e=0;e<E_NUM;e++) local[e]=0;
  #pragma unroll
  for (int j=0;j<4;j++){
    const int e = e_loc[j];
    int pos = 0;
    #pragma unroll
    for (int ee=0; ee<E_NUM; ee++)
      if (e == ee) pos = offs_s[ee] + wsum[ee][wv] + pre[ee] + local[ee];
    #pragma unroll
    for (int ee=0; ee<E_NUM; ee++) local[ee] += (e == ee) ? 1 : 0;
    const int entry = tid*4 + j;
    assign_token[pos] = entry >> 1;
    assign_w[pos]     = w_loc[j];
    token_slot[entry] = pos;
  }
}

// ======= persistent gate+up GEMM: 256 blocks pull tiles+conv chunks from a work queue =====
// Per-tile body = r14-proven BK=32, 4-buf, 3-deep counted pipeline. LDS 128 KB, 1 blk/CU.
__global__ __launch_bounds__(512,1) void gateup_fused(
    const unsigned short* __restrict__ xb,
    unsigned short* __restrict__ wb,
    const float* __restrict__ Wsd_f, const float* __restrict__ Wd_f,
    unsigned short* __restrict__ h_shared,
    unsigned short* __restrict__ h_routed,
    const int* __restrict__ tile_rowbase, const int* __restrict__ tile_e,
    const int* __restrict__ tile_valid, const int* __restrict__ n_rt,
    const int* __restrict__ assign_token,
    int* __restrict__ work_ctr)
{
  __shared__ __align__(16) char As[4][256*64];   // 64 KB
  __shared__ __align__(16) char Bg[4][128*64];   // 32 KB
  __shared__ __align__(16) char Bu[4][128*64];   // 32 KB
  __shared__ int item_s;

  const int tid  = threadIdx.x;
  const int lane = tid & 63;
  const int wave = tid >> 6;       // 0..7
  const int wr = wave >> 1;        // 0..3
  const int wc = wave & 1;         // 0..1

  const int nrt = n_rt[0];
  const int ng  = GU_SH_TILE + nrt*11;     // dense GEMM tiles, no dead items
  const int TOT = ng + GU_CONVCH;

  const int arow0 = wr*64 + (lane & 15);
  const int brow0 = wc*64 + (lane & 15);
  const int sread = (lane >> 4) << 4;

  for(;;){
    __syncthreads();                        // fence: prior tile's item_s reads / LDS reads done
    if (tid == 0) item_s = atomicAdd(work_ctr, 1);
    __syncthreads();
    const int it = item_s;
    if (it >= TOT) return;

    // Bresenham interleave: GU_CONVCH conv items spread evenly through [0,TOT)
    const int cbefore = (int)(((long)it * GU_CONVCH) / TOT);
    const bool isconv = (int)(((long)(it+1) * GU_CONVCH) / TOT) > cbefore;
    if (isconv){
      const int cidx = cbefore;             // each cidx in [0,GU_CONVCH) occurs exactly once
      const long nchunk = (long)(W_TOT - O_WSD) / 8;  // 3,604,480
      for (long j = (long)cidx*512 + tid; j < nchunk; j += (long)GU_CONVCH*512){
        const long e0 = (long)O_WSD + j * 8;
        const float* src; long lo;
        if (e0 < (long)O_WD){ src = Wsd_f; lo = e0 - O_WSD; } else { src = Wd_f; lo = e0 - O_WD; }
        const float4 va = ((const float4*)(src + lo))[0];
        const float4 vb = ((const float4*)(src + lo))[1];
        u16x4 h0, h1;
        h0[0]=f2bf(va.x); h0[1]=f2bf(va.y); h0[2]=f2bf(va.z); h0[3]=f2bf(va.w);
        h1[0]=f2bf(vb.x); h1[1]=f2bf(vb.y); h1[2]=f2bf(vb.z); h1[3]=f2bf(vb.w);
        ((u16x4*)(wb + e0))[0] = h0;
        ((u16x4*)(wb + e0))[1] = h1;
      }
      continue;
    }
    const int g = it - cbefore;             // dense [0, ng)

    int nt, rowbase, valid, gather;
    const unsigned short *wg_base, *wu_base;
    unsigned short* H; int N;
    if (g < GU_SH_TILE){
      nt = g >> 3; const int mtile = g & 7;
      rowbase = mtile*256; valid = 256; gather = 0;
      wg_base = wb + O_WSG + (size_t)(nt*128) * D_HID;
      wu_base = wb + O_WSU + (size_t)(nt*128) * D_HID;
      H = h_shared; N = FS_SH;
    } else {
      const int rb = g - GU_SH_TILE;
      const int tile = rb % nrt;
      nt = rb / nrt;                        // 0..10
      rowbase = tile_rowbase[tile];
      valid   = tile_valid[tile];
      const int e = tile_e[tile];
      gather = 1;
      wg_base = wb + O_WG + ((size_t)e*F_EXP + nt*128) * D_HID;
      wu_base = wb + O_WU + ((size_t)e*F_EXP + nt*128) * D_HID;
      H = h_routed; N = F_EXP;
    }

    f32x4 accg[4][4], accu[4][4];
    const f32x4 z = {0.f,0.f,0.f,0.f};
    #pragma unroll
    for (int m=0;m<4;m++)
      #pragma unroll
      for (int n=0;n<4;n++){ accg[m][n]=z; accu[m][n]=z; }

    const char* asrc[2];
    const int rowmax = rowbase + valid - 1;
    #pragma unroll
    for (int p=0;p<2;p++){
      const int c = p*512 + tid;
      const int row = c >> 2, slot = c & 3;
      const int col16 = slot ^ ((row>>1)&3);
      int idx = rowbase + row;
      if (idx > rowmax) idx = rowmax;
      const size_t grow = gather ? (size_t)assign_token[idx] : (size_t)idx;
      asrc[p] = (const char*)(xb + grow * (size_t)D_HID) + (col16<<4);
    }
    const int brw = tid >> 2, bsl = tid & 3;
    const int bcol16 = bsl ^ ((brw>>1)&3);
    const char* gsrc = (const char*)(wg_base + (size_t)brw * D_HID) + (bcol16<<4);
    const char* usrc = (const char*)(wu_base + (size_t)brw * D_HID) + (bcol16<<4);

    auto stage = [&](int bi, int kt){     // 4 loads per thread
      #pragma unroll
      for (int p=0;p<2;p++)
        __builtin_amdgcn_global_load_lds(
          (const AS1 void*)(asrc[p] + kt*64),
          (AS3 void*)(&As[bi][(p*512 + tid)*16]), 16, 0, 0);
      __builtin_amdgcn_global_load_lds(
          (const AS1 void*)(gsrc + kt*64),
          (AS3 void*)(&Bg[bi][tid*16]), 16, 0, 0);
      __builtin_amdgcn_global_load_lds(
          (const AS1 void*)(usrc + kt*64),
          (AS3 void*)(&Bu[bi][tid*16]), 16, 0, 0);
    };

    const int nK = D_HID / 32;   // 64
    stage(0,0); stage(1,1); stage(2,2);   // 12 loads in flight (3 tiles)

    #pragma unroll 1
    for (int kt = 0; kt < nK; ++kt){
      if (kt < nK-2)       asm volatile("s_waitcnt vmcnt(8)\n\ts_barrier" ::: "memory");
      else if (kt == nK-2) asm volatile("s_waitcnt vmcnt(4)\n\ts_barrier" ::: "memory");
      else                 asm volatile("s_waitcnt vmcnt(0)\n\ts_barrier" ::: "memory");
      const int bi = kt & 3;
      bf16x8 a[4], bgr[4], bur[4];
      #pragma unroll
      for (int m=0;m<4;m++){
        const int r = arow0 + m*16;
        a[m] = *(const bf16x8*)(&As[bi][r*64 + (sread ^ (((r>>1)&3)<<4))]);
      }
      #pragma unroll
      for (int n=0;n<4;n++){
        const int r = brow0 + n*16;
        const int ofs = r*64 + (sread ^ (((r>>1)&3)<<4));
        bgr[n] = *(const bf16x8*)(&Bg[bi][ofs]);
        bur[n] = *(const bf16x8*)(&Bu[bi][ofs]);
      }
      if (kt + 3 < nK) stage((kt+3)&3, kt+3);
      #pragma unroll
      for (int m=0;m<4;m++)
        #pragma unroll
        for (int n=0;n<4;n++){
          accg[m][n] = __builtin_amdgcn_mfma_f32_16x16x32_bf16(a[m], bgr[n], accg[m][n], 0,0,0);
          accu[m][n] = __builtin_amdgcn_mfma_f32_16x16x32_bf16(a[m], bur[n], accu[m][n], 0,0,0);
        }
    }

    const int colbase = nt*128 + wc*64;
    #pragma unroll
    for (int m=0;m<4;m++){
      #pragma unroll
      for (int r=0;r<4;r++){
        const int rr = wr*64 + m*16 + ((lane >> 4) << 2) + r;
        if (rr < valid){
          unsigned short* orow = H + (size_t)(rowbase + rr) * N;
          #pragma unroll
          for (int n=0;n<4;n++){
            const int col = colbase + n*16 + (lane & 15);
            const float g2 = accg[m][n][r];
            const float u = accu[m][n][r];
            const float h = (g2 / (1.f + __expf(-g2))) * u;
            orow[col] = f2bf(h);
          }
        }
      }
    }
  }
}

// ====== down GEMM: BM=256, BN=256, BK=32, 4-buf, 3-deep; grid = exactly 256 blocks ======
__global__ __launch_bounds__(512,2) void down_fused(
    const unsigned short* __restrict__ h_shared,
    const unsigned short* __restrict__ h_routed,
    const unsigned short* __restrict__ wb,
    float* __restrict__ out, unsigned short* __restrict__ y_routed,
    const int* __restrict__ tile_rowbase, const int* __restrict__ tile_e,
    const int* __restrict__ tile_valid, const int* __restrict__ n_rt)
{
  __shared__ __align__(16) char As[4][256*64];   // 64 KB
  __shared__ __align__(16) char Bs[4][256*64];   // 64 KB

  const int tid  = threadIdx.x;
  const int braw = blockIdx.x;
  const int b = (braw % 8) * (DN_GRID/8) + braw / 8;   // XCD swizzle (256 = 8*32)
  const int lane = tid & 63;
  const int wave = tid >> 6;
  const int wr = wave >> 1, wc = wave & 1;

  int nt, rowbase, valid, routed, K;
  const unsigned short *A, *w_base;
  if (b < DN_SH_BLK){
    nt = b >> 3; const int mtile = b & 7;
    rowbase = mtile*256; valid = 256; routed = 0;
    A = h_shared; K = FS_SH;
    w_base = wb + O_WSD + (size_t)(nt*256) * FS_SH;
  } else {
    const int rb = b - DN_SH_BLK;
    const int tile = rb % MAXT;
    nt = rb / MAXT;                             // 0..7
    if (tile >= n_rt[0]) return;
    rowbase = tile_rowbase[tile];
    valid   = tile_valid[tile];
    const int e = tile_e[tile];
    routed = 1;
    A = h_routed; K = F_EXP;
    w_base = wb + O_WD + ((size_t)e*D_HID + nt*256) * F_EXP;
  }
  const size_t K2 = (size_t)K * 2;

  f32x4 acc[4][8];
  const f32x4 z = {0.f,0.f,0.f,0.f};
  #pragma unroll
  for (int m=0;m<4;m++)
    #pragma unroll
    for (int n=0;n<8;n++) acc[m][n]=z;

  const char* asrc[2];
  const int rowmax = rowbase + valid - 1;
  #pragma unroll
  for (int p=0;p<2;p++){
    const int c = p*512 + tid;
    const int row = c >> 2, slot = c & 3;
    const int col16 = slot ^ ((row>>1)&3);
    int idx = rowbase + row;
    if (idx > rowmax) idx = rowmax;
    asrc[p] = (const char*)A + (size_t)idx * K2 + (col16<<4);
  }
  const char* bsrc[2];
  #pragma unroll
  for (int p=0;p<2;p++){
    const int c = p*512 + tid;
    const int row = c >> 2, slot = c & 3;
    const int col16 = slot ^ ((row>>1)&3);
    bsrc[p] = (const char*)(w_base + (size_t)row * K) + (col16<<4);
  }

  auto stage = [&](int bi, int kt){     // 4 loads per thread
    #pragma unroll
    for (int p=0;p<2;p++)
      __builtin_amdgcn_global_load_lds(
        (const AS1 void*)(asrc[p] + kt*64),
        (AS3 void*)(&As[bi][(p*512 + tid)*16]), 16, 0, 0);
    #pragma unroll
    for (int p=0;p<2;p++)
      __builtin_amdgcn_global_load_lds(
        (const AS1 void*)(bsrc[p] + kt*64),
        (AS3 void*)(&Bs[bi][(p*512 + tid)*16]), 16, 0, 0);
  };

  const int nK = K / 32;       // 88 or 44
  stage(0,0); stage(1,1); stage(2,2);   // 12 outstanding

  const int arow0 = wr*64 + (lane & 15);
  const int brow0 = wc*128 + (lane & 15);
  const int sread = (lane >> 4) << 4;

  #pragma unroll 1
  for (int kt = 0; kt < nK; ++kt){
    if (kt < nK-2)       asm volatile("s_waitcnt vmcnt(8)\n\ts_barrier" ::: "memory");
    else if (kt == nK-2) asm volatile("s_waitcnt vmcnt(4)\n\ts_barrier" ::: "memory");
    else                 asm volatile("s_waitcnt vmcnt(0)\n\ts_barrier" ::: "memory");
    const int bi = kt & 3;
    bf16x8 a[4], bb[8];
    #pragma unroll
    for (int m=0;m<4;m++){
      const int r = arow0 + m*16;
      a[m] = *(const bf16x8*)(&As[bi][r*64 + (sread ^ (((r>>1)&3)<<4))]);
    }
    #pragma unroll
    for (int n=0;n<8;n++){
      const int r = brow0 + n*16;
      bb[n] = *(const bf16x8*)(&Bs[bi][r*64 + (sread ^ (((r>>1)&3)<<4))]);
    }
    if (kt + 3 < nK) stage((kt+3)&3, kt+3);
    #pragma unroll
    for (int m=0;m<4;m++)
      #pragma unroll
      for (int n=0;n<8;n++)
        acc[m][n] = __builtin_amdgcn_mfma_f32_16x16x32_bf16(a[m], bb[n], acc[m][n], 0,0,0);
  }

  const int colbase = nt*256 + wc*128;
  #pragma unroll
  for (int m=0;m<4;m++){
    #pragma unroll
    for (int r=0;r<4;r++){
      const int rr = wr*64 + m*16 + ((lane >> 4) << 2) + r;
      if (rr < valid){
        if (routed){
          unsigned short* orow = y_routed + (size_t)(rowbase + rr) * D_HID;
          #pragma unroll
          for (int n=0;n<8;n++){
            const int col = colbase + n*16 + (lane & 15);
            orow[col] = f2bf(acc[m][n][r]);
          }
        } else {
          float* orow = out + (size_t)(rowbase + rr) * D_HID;
          #pragma unroll
          for (int n=0;n<8;n++){
            const int col = colbase + n*16 + (lane & 15);
            orow[col] = acc[m][n][r];
          }
        }
      }
    }
  }
}

// ---------------- combine: out += w0*y[slot0] + w1*y[slot1]  (y is bf16, unweighted) ----
__global__ void combine_kernel(float* __restrict__ out, const unsigned short* __restrict__ y,
                               const int* __restrict__ token_slot,
                               const float* __restrict__ topk_w){
  const int i  = blockIdx.x * blockDim.x + threadIdx.x;   // float4 index into out
  const int t  = i >> 9;
  const int r4 = i & 511;
  const int s0 = token_slot[t*2+0];
  const int s1 = token_slot[t*2+1];
  const float w0 = topk_w[t*2+0];
  const float w1 = topk_w[t*2+1];
  const u16x4 a = ((const u16x4*)(y + (size_t)s0 * D_HID))[r4];
  const u16x4 bq = ((const u16x4*)(y + (size_t)s1 * D_HID))[r4];
  float4 o = ((float4*)out)[i];
  o.x += w0*bf2f(a[0]) + w1*bf2f(bq[0]);
  o.y += w0*bf2f(a[1]) + w1*bf2f(bq[1]);
  o.z += w0*bf2f(a[2]) + w1*bf2f(bq[2]);
  o.w += w0*bf2f(a[3]) + w1*bf2f(bq[3]);
  ((float4*)out)[i] = o;
}

extern "C" void kernel_launch(void* const* d_in, const int* in_sizes, int n_in,
                              void* d_out, int out_size, void* d_ws, size_t ws_size,
                              hipStream_t stream){
  const float* x   = (const float*)d_in[0];
  const float* Wr  = (const float*)d_in[1];
  const float* Wg  = (const float*)d_in[2];
  const float* Wu  = (const float*)d_in[3];
  const float* Wd  = (const float*)d_in[4];
  const float* Wsg = (const float*)d_in[5];
  const float* Wsu = (const float*)d_in[6];
  const float* Wsd = (const float*)d_in[7];
  float* out = (float*)d_out;
  (void)in_sizes; (void)n_in; (void)out_size; (void)ws_size;

  char* ws = (char*)d_ws;
  size_t off = 0;
  auto alloc = [&](size_t bytes)->char*{
    char* p = ws + off; off += (bytes + 255) & ~(size_t)255; return p;
  };

  unsigned short* wb       = (unsigned short*)alloc((size_t)W_TOT * 2);
  unsigned short* xb       = (unsigned short*)alloc((size_t)T_TOK * D_HID * 2);
  unsigned short* h_shared = (unsigned short*)alloc((size_t)T_TOK * FS_SH * 2);
  unsigned short* h_routed = (unsigned short*)alloc((size_t)T_TOK * 2 * F_EXP * 2);
  unsigned short* y_routed = (unsigned short*)alloc((size_t)T_TOK * 2 * D_HID * 2);
  int*   topk_e       = (int*)alloc(T_TOK*2*sizeof(int));
  float* topk_w       = (float*)alloc(T_TOK*2*sizeof(float));
  int*   cnt          = (int*)alloc(E_NUM*sizeof(int));
  int*   offs         = (int*)alloc(E_NUM*sizeof(int));
  int*   assign_token = (int*)alloc(T_TOK*2*sizeof(int));
  float* assign_w     = (float*)alloc(T_TOK*2*sizeof(float));
  int*   token_slot   = (int*)alloc(T_TOK*2*sizeof(int));
  int*   tile_rowbase = (int*)alloc(MAXT*sizeof(int));
  int*   tile_e       = (int*)alloc(MAXT*sizeof(int));
  int*   tile_valid   = (int*)alloc(MAXT*sizeof(int));
  int*   n_rt         = (int*)alloc(sizeof(int));
  int*   work_ctr     = (int*)alloc(sizeof(int));

  prep_kernel<<<RT_BLK + WC_BLK, 256, 0, stream>>>(
      x, Wr, Wsg, Wsu, Wg, Wu, xb, wb, topk_e, topk_w);
  build_lists_kernel<<<1, 1024, 0, stream>>>(topk_e, topk_w, cnt, offs,
      assign_token, assign_w, token_slot, tile_rowbase, tile_e, tile_valid, n_rt, work_ctr);

  gateup_fused<<<GU_GRID, 512, 0, stream>>>(
      xb, wb, Wsd, Wd, h_shared, h_routed, tile_rowbase, tile_e, tile_valid, n_rt,
      assign_token, work_ctr);
  down_fused<<<DN_GRID, 512, 0, stream>>>(
      h_shared, h_routed, wb, out, y_routed, tile_rowbase, tile_e, tile_valid, n_rt);

  combine_kernel<<<(T_TOK*D_HID/4)/256, 256, 0, stream>>>(out, y_routed, token_slot, topk_w);
}

// Round 17
// 326.367 us; speedup vs baseline: 1.0692x; 1.0291x over previous
//
#include <hip/hip_runtime.h>
#include <hip/hip_bf16.h>

#define D_HID 2048
#define F_EXP 1408
#define E_NUM 8
#define FS_SH 2816
#define T_TOK 2048

// bf16 element offsets inside the converted-weight block wb
#define O_WSG 0
#define O_WSU 5767168
#define O_WG  11534336
#define O_WU  34603008
#define O_WSD 57671680
#define O_WD  63438848
#define W_TOT 86507520

#define MAXT 24          // routed 256-row tiles
#define GU_SH_BLK 176
#define GU_GEMM   440    // = 8*55
#define GU_CONV   184
#define DN_SH_BLK 64     // shared down: 8 nt(256) * 8 mt
#define DN_GRID   256    // 64 + 24*8  (= 8*32) -> exactly one scheduling round
#define RT_BLK    512
#define WC_BLK    1408

typedef __attribute__((ext_vector_type(8))) short bf16x8;
typedef __attribute__((ext_vector_type(4))) float f32x4;
typedef __attribute__((ext_vector_type(4))) unsigned short u16x4;

#define AS1 __attribute__((address_space(1)))
#define AS3 __attribute__((address_space(3)))

__device__ __forceinline__ unsigned short f2bf(float f){
  unsigned u = __float_as_uint(f);
  u += 0x7fffu + ((u >> 16) & 1u);          // RNE
  return (unsigned short)(u >> 16);
}
__device__ __forceinline__ float bf2f(unsigned short h){
  return __uint_as_float(((unsigned)h) << 16);
}

// ---------------- prep: router (+x->bf16) and gate/up weight fp32->bf16 ----------------
__global__ __launch_bounds__(256) void prep_kernel(
    const float* __restrict__ x,  const float* __restrict__ Wr,
    const float* __restrict__ Wsg, const float* __restrict__ Wsu,
    const float* __restrict__ Wg,  const float* __restrict__ Wu,
    unsigned short* __restrict__ xb, unsigned short* __restrict__ wb,
    int* __restrict__ topk_e, float* __restrict__ topk_w)
{
  const int b = blockIdx.x;
  if (b >= RT_BLK){
    const int cb = b - RT_BLK;
    const long nchunk = (long)O_WSD / 8;    // 7,208,960
    for (long i = (long)cb*256 + threadIdx.x; i < nchunk; i += (long)WC_BLK*256){
      const long e0 = i * 8;
      const float* src; long lo;
      if      (e0 < (long)O_WSU){ src = Wsg; lo = e0; }
      else if (e0 < (long)O_WG ){ src = Wsu; lo = e0 - O_WSU; }
      else if (e0 < (long)O_WU ){ src = Wg;  lo = e0 - O_WG;  }
      else                      { src = Wu;  lo = e0 - O_WU;  }
      const float4 va = ((const float4*)(src + lo))[0];
      const float4 vb = ((const float4*)(src + lo))[1];
      u16x4 h0, h1;
      h0[0]=f2bf(va.x); h0[1]=f2bf(va.y); h0[2]=f2bf(va.z); h0[3]=f2bf(va.w);
      h1[0]=f2bf(vb.x); h1[1]=f2bf(vb.y); h1[2]=f2bf(vb.z); h1[3]=f2bf(vb.w);
      ((u16x4*)(wb + e0))[0] = h0;
      ((u16x4*)(wb + e0))[1] = h1;
    }
    return;
  }
  const int lane = threadIdx.x & 63;
  const int t = b*4 + (threadIdx.x >> 6);
  const float* xt = x + (size_t)t * D_HID;
  unsigned short* xbt = xb + (size_t)t * D_HID;
  float acc[E_NUM];
  #pragma unroll
  for (int e=0;e<E_NUM;e++) acc[e]=0.f;
  #pragma unroll
  for (int j=0;j<8;j++){
    const int d = j*256 + lane*4;
    const float4 v = *(const float4*)(xt + d);
    u16x4 h;
    h[0]=f2bf(v.x); h[1]=f2bf(v.y); h[2]=f2bf(v.z); h[3]=f2bf(v.w);
    *(u16x4*)(xbt + d) = h;
    #pragma unroll
    for (int e=0;e<E_NUM;e++){
      const float4 w = *(const float4*)(Wr + e*D_HID + d);
      acc[e] += v.x*w.x + v.y*w.y + v.z*w.z + v.w*w.w;
    }
  }
  #pragma unroll
  for (int e=0;e<E_NUM;e++){
    #pragma unroll
    for (int off=32; off>0; off>>=1) acc[e] += __shfl_xor(acc[e], off);
  }
  if (lane==0){
    float m = acc[0];
    #pragma unroll
    for (int e=1;e<E_NUM;e++) m = fmaxf(m, acc[e]);
    float p[E_NUM]; float s = 0.f;
    #pragma unroll
    for (int e=0;e<E_NUM;e++){ p[e] = expf(acc[e]-m); s += p[e]; }
    const float inv = 1.f/s;
    int i0=0; float b0=p[0];
    #pragma unroll
    for (int e=1;e<E_NUM;e++) if (p[e] > b0){ b0=p[e]; i0=e; }
    int i1=-1; float b1=-1.f;
    #pragma unroll
    for (int e=0;e<E_NUM;e++) if (e!=i0 && p[e] > b1){ b1=p[e]; i1=e; }
    topk_e[t*2+0]=i0; topk_e[t*2+1]=i1;
    topk_w[t*2+0]=b0*inv; topk_w[t*2+1]=b1*inv;
  }
}

// ---------------- deterministic expert-grouped list build + 256-row tile records --------
__global__ __launch_bounds__(1024) void build_lists_kernel(
    const int* __restrict__ topk_e, const float* __restrict__ topk_w,
    int* __restrict__ cnt, int* __restrict__ offs,
    int* __restrict__ assign_token, float* __restrict__ assign_w,
    int* __restrict__ token_slot,
    int* __restrict__ tile_rowbase, int* __restrict__ tile_e,
    int* __restrict__ tile_valid, int* __restrict__ n_rt)
{
  const int tid  = threadIdx.x;
  const int lane = tid & 63;
  const int wv   = tid >> 6;                 // 16 waves
  __shared__ int wsum[E_NUM][16];
  __shared__ int tot_s[E_NUM];
  __shared__ int offs_s[E_NUM];

  int   e_loc[4];
  float w_loc[4];
  #pragma unroll
  for (int j=0;j<4;j++){ e_loc[j]=topk_e[tid*4+j]; w_loc[j]=topk_w[tid*4+j]; }

  int c[E_NUM];
  #pragma unroll
  for (int e=0;e<E_NUM;e++){
    int s = 0;
    #pragma unroll
    for (int j=0;j<4;j++) s += (e_loc[j]==e) ? 1 : 0;
    c[e] = s;
  }
  int pre[E_NUM];
  #pragma unroll
  for (int e=0;e<E_NUM;e++){
    int v = c[e];
    #pragma unroll
    for (int off=1; off<64; off<<=1){
      int t = __shfl_up(v, off);
      if (lane >= off) v += t;
    }
    if (lane==63) wsum[e][wv] = v;
    pre[e] = v - c[e];
  }
  __syncthreads();
  if (tid < E_NUM){
    int s = 0;
    #pragma unroll
    for (int w=0; w<16; w++){ int t = wsum[tid][w]; wsum[tid][w] = s; s += t; }
    tot_s[tid] = s;
    cnt[tid]   = s;
  }
  __syncthreads();
  if (tid == 0){
    int s = 0;
    #pragma unroll
    for (int e=0;e<E_NUM;e++){ offs_s[e] = s; offs[e] = s; s += tot_s[e]; }
    int ntl = 0;
    for (int e=0;e<E_NUM;e++){
      for (int r=0; r<tot_s[e]; r+=256){
        tile_rowbase[ntl] = offs_s[e] + r;
        tile_e[ntl]       = e;
        int v = tot_s[e] - r; if (v > 256) v = 256;
        tile_valid[ntl]   = v;
        ntl++;
      }
    }
    n_rt[0] = ntl;
    for (int i=ntl;i<MAXT;i++){ tile_rowbase[i]=0; tile_e[i]=0; tile_valid[i]=0; }
  }
  __syncthreads();
  int local[E_NUM];
  #pragma unroll
  for (int e=0;e<E_NUM;e++) local[e]=0;
  #pragma unroll
  for (int j=0;j<4;j++){
    const int e = e_loc[j];
    int pos = 0;
    #pragma unroll
    for (int ee=0; ee<E_NUM; ee++)
      if (e == ee) pos = offs_s[ee] + wsum[ee][wv] + pre[ee] + local[ee];
    #pragma unroll
    for (int ee=0; ee<E_NUM; ee++) local[ee] += (e == ee) ? 1 : 0;
    const int entry = tid*4 + j;
    assign_token[pos] = entry >> 1;
    assign_w[pos]     = w_loc[j];
    token_slot[entry] = pos;
  }
}

// ================= gate+up GEMM (r12 proven): BK=32, 4-buf, 3-deep counted pipeline =====
__global__ __launch_bounds__(512,1) void gateup_fused(
    const unsigned short* __restrict__ xb,
    unsigned short* __restrict__ wb,
    const float* __restrict__ Wsd_f, const float* __restrict__ Wd_f,
    unsigned short* __restrict__ h_shared,
    unsigned short* __restrict__ h_routed,
    const int* __restrict__ tile_rowbase, const int* __restrict__ tile_e,
    const int* __restrict__ tile_valid, const int* __restrict__ n_rt,
    const int* __restrict__ assign_token)
{
  __shared__ __align__(16) char As[4][256*64];   // 64 KB
  __shared__ __align__(16) char Bg[4][128*64];   // 32 KB
  __shared__ __align__(16) char Bu[4][128*64];   // 32 KB

  const int tid  = threadIdx.x;
  const int braw = blockIdx.x;

  if (braw >= GU_GEMM){
    const int cb = braw - GU_GEMM;                  // 0..183
    const long nchunk = (long)(W_TOT - O_WSD) / 8;  // 3,604,480
    for (long i = (long)cb*512 + tid; i < nchunk; i += (long)GU_CONV*512){
      const long e0 = (long)O_WSD + i * 8;
      const float* src; long lo;
      if (e0 < (long)O_WD){ src = Wsd_f; lo = e0 - O_WSD; } else { src = Wd_f; lo = e0 - O_WD; }
      const float4 va = ((const float4*)(src + lo))[0];
      const float4 vb = ((const float4*)(src + lo))[1];
      u16x4 h0, h1;
      h0[0]=f2bf(va.x); h0[1]=f2bf(va.y); h0[2]=f2bf(va.z); h0[3]=f2bf(va.w);
      h1[0]=f2bf(vb.x); h1[1]=f2bf(vb.y); h1[2]=f2bf(vb.z); h1[3]=f2bf(vb.w);
      ((u16x4*)(wb + e0))[0] = h0;
      ((u16x4*)(wb + e0))[1] = h1;
    }
    return;
  }

  const int b = (braw % 8) * (GU_GEMM/8) + braw / 8;   // XCD swizzle (440 = 8*55)

  const int lane = tid & 63;
  const int wave = tid >> 6;       // 0..7
  const int wr = wave >> 1;        // 0..3
  const int wc = wave & 1;         // 0..1

  int nt, rowbase, valid, gather;
  const unsigned short *wg_base, *wu_base;
  unsigned short* H; int N;
  if (b < GU_SH_BLK){
    nt = b >> 3; const int mtile = b & 7;
    rowbase = mtile*256; valid = 256; gather = 0;
    wg_base = wb + O_WSG + (size_t)(nt*128) * D_HID;
    wu_base = wb + O_WSU + (size_t)(nt*128) * D_HID;
    H = h_shared; N = FS_SH;
  } else {
    const int rb = b - GU_SH_BLK;
    const int tile = rb % MAXT;
    nt = rb / MAXT;                              // 0..10
    if (tile >= n_rt[0]) return;
    rowbase = tile_rowbase[tile];
    valid   = tile_valid[tile];
    const int e = tile_e[tile];
    gather = 1;
    wg_base = wb + O_WG + ((size_t)e*F_EXP + nt*128) * D_HID;
    wu_base = wb + O_WU + ((size_t)e*F_EXP + nt*128) * D_HID;
    H = h_routed; N = F_EXP;
  }

  f32x4 accg[4][4], accu[4][4];
  const f32x4 z = {0.f,0.f,0.f,0.f};
  #pragma unroll
  for (int m=0;m<4;m++)
    #pragma unroll
    for (int n=0;n<4;n++){ accg[m][n]=z; accu[m][n]=z; }

  const char* asrc[2];
  const int rowmax = rowbase + valid - 1;
  #pragma unroll
  for (int p=0;p<2;p++){
    const int c = p*512 + tid;
    const int row = c >> 2, slot = c & 3;
    const int col16 = slot ^ ((row>>1)&3);
    int idx = rowbase + row;
    if (idx > rowmax) idx = rowmax;
    const size_t grow = gather ? (size_t)assign_token[idx] : (size_t)idx;
    asrc[p] = (const char*)(xb + grow * (size_t)D_HID) + (col16<<4);
  }
  const int brw = tid >> 2, bsl = tid & 3;
  const int bcol16 = bsl ^ ((brw>>1)&3);
  const char* gsrc = (const char*)(wg_base + (size_t)brw * D_HID) + (bcol16<<4);
  const char* usrc = (const char*)(wu_base + (size_t)brw * D_HID) + (bcol16<<4);

  auto stage = [&](int bi, int kt){     // 4 loads per thread
    #pragma unroll
    for (int p=0;p<2;p++)
      __builtin_amdgcn_global_load_lds(
        (const AS1 void*)(asrc[p] + kt*64),
        (AS3 void*)(&As[bi][(p*512 + tid)*16]), 16, 0, 0);
    __builtin_amdgcn_global_load_lds(
        (const AS1 void*)(gsrc + kt*64),
        (AS3 void*)(&Bg[bi][tid*16]), 16, 0, 0);
    __builtin_amdgcn_global_load_lds(
        (const AS1 void*)(usrc + kt*64),
        (AS3 void*)(&Bu[bi][tid*16]), 16, 0, 0);
  };

  const int nK = D_HID / 32;   // 64
  stage(0,0); stage(1,1); stage(2,2);   // 12 loads in flight (3 tiles)

  const int arow0 = wr*64 + (lane & 15);
  const int brow0 = wc*64 + (lane & 15);
  const int sread = (lane >> 4) << 4;

  #pragma unroll 1
  for (int kt = 0; kt < nK; ++kt){
    if (kt < nK-2)       asm volatile("s_waitcnt vmcnt(8)\n\ts_barrier" ::: "memory");
    else if (kt == nK-2) asm volatile("s_waitcnt vmcnt(4)\n\ts_barrier" ::: "memory");
    else                 asm volatile("s_waitcnt vmcnt(0)\n\ts_barrier" ::: "memory");
    const int bi = kt & 3;
    bf16x8 a[4], bgr[4], bur[4];
    #pragma unroll
    for (int m=0;m<4;m++){
      const int r = arow0 + m*16;
      a[m] = *(const bf16x8*)(&As[bi][r*64 + (sread ^ (((r>>1)&3)<<4))]);
    }
    #pragma unroll
    for (int n=0;n<4;n++){
      const int r = brow0 + n*16;
      const int ofs = r*64 + (sread ^ (((r>>1)&3)<<4));
      bgr[n] = *(const bf16x8*)(&Bg[bi][ofs]);
      bur[n] = *(const bf16x8*)(&Bu[bi][ofs]);
    }
    if (kt + 3 < nK) stage((kt+3)&3, kt+3);   // overwrites buf read at iter kt-1 (safe)
    #pragma unroll
    for (int m=0;m<4;m++)
      #pragma unroll
      for (int n=0;n<4;n++){
        accg[m][n] = __builtin_amdgcn_mfma_f32_16x16x32_bf16(a[m], bgr[n], accg[m][n], 0,0,0);
        accu[m][n] = __builtin_amdgcn_mfma_f32_16x16x32_bf16(a[m], bur[n], accu[m][n], 0,0,0);
      }
  }

  const int colbase = nt*128 + wc*64;
  #pragma unroll
  for (int m=0;m<4;m++){
    #pragma unroll
    for (int r=0;r<4;r++){
      const int rr = wr*64 + m*16 + ((lane >> 4) << 2) + r;
      if (rr < valid){
        unsigned short* orow = H + (size_t)(rowbase + rr) * N;
        #pragma unroll
        for (int n=0;n<4;n++){
          const int col = colbase + n*16 + (lane & 15);
          const float g2 = accg[m][n][r];
          const float u = accu[m][n][r];
          const float h = (g2 / (1.f + __expf(-g2))) * u;
          orow[col] = f2bf(h);
        }
      }
    }
  }
}

// ====== down GEMM: BM=256, BN=256, BK=32, 4-buf, 3-deep; grid = exactly 256 blocks ======
__global__ __launch_bounds__(512,2) void down_fused(
    const unsigned short* __restrict__ h_shared,
    const unsigned short* __restrict__ h_routed,
    const unsigned short* __restrict__ wb,
    float* __restrict__ out, unsigned short* __restrict__ y_routed,
    const int* __restrict__ tile_rowbase, const int* __restrict__ tile_e,
    const int* __restrict__ tile_valid, const int* __restrict__ n_rt)
{
  __shared__ __align__(16) char As[4][256*64];   // 64 KB
  __shared__ __align__(16) char Bs[4][256*64];   // 64 KB

  const int tid  = threadIdx.x;
  const int braw = blockIdx.x;
  const int b = (braw % 8) * (DN_GRID/8) + braw / 8;   // XCD swizzle (256 = 8*32)
  const int lane = tid & 63;
  const int wave = tid >> 6;
  const int wr = wave >> 1, wc = wave & 1;

  int nt, rowbase, valid, routed, K;
  const unsigned short *A, *w_base;
  if (b < DN_SH_BLK){
    nt = b >> 3; const int mtile = b & 7;
    rowbase = mtile*256; valid = 256; routed = 0;
    A = h_shared; K = FS_SH;
    w_base = wb + O_WSD + (size_t)(nt*256) * FS_SH;
  } else {
    const int rb = b - DN_SH_BLK;
    const int tile = rb % MAXT;
    nt = rb / MAXT;                             // 0..7
    if (tile >= n_rt[0]) return;
    rowbase = tile_rowbase[tile];
    valid   = tile_valid[tile];
    const int e = tile_e[tile];
    routed = 1;
    A = h_routed; K = F_EXP;
    w_base = wb + O_WD + ((size_t)e*D_HID + nt*256) * F_EXP;
  }
  const size_t K2 = (size_t)K * 2;

  f32x4 acc[4][8];
  const f32x4 z = {0.f,0.f,0.f,0.f};
  #pragma unroll
  for (int m=0;m<4;m++)
    #pragma unroll
    for (int n=0;n<8;n++) acc[m][n]=z;

  const char* asrc[2];
  const int rowmax = rowbase + valid - 1;
  #pragma unroll
  for (int p=0;p<2;p++){
    const int c = p*512 + tid;
    const int row = c >> 2, slot = c & 3;
    const int col16 = slot ^ ((row>>1)&3);
    int idx = rowbase + row;
    if (idx > rowmax) idx = rowmax;
    asrc[p] = (const char*)A + (size_t)idx * K2 + (col16<<4);
  }
  const char* bsrc[2];
  #pragma unroll
  for (int p=0;p<2;p++){
    const int c = p*512 + tid;
    const int row = c >> 2, slot = c & 3;
    const int col16 = slot ^ ((row>>1)&3);
    bsrc[p] = (const char*)(w_base + (size_t)row * K) + (col16<<4);
  }

  auto stage = [&](int bi, int kt){     // 4 loads per thread
    #pragma unroll
    for (int p=0;p<2;p++)
      __builtin_amdgcn_global_load_lds(
        (const AS1 void*)(asrc[p] + kt*64),
        (AS3 void*)(&As[bi][(p*512 + tid)*16]), 16, 0, 0);
    #pragma unroll
    for (int p=0;p<2;p++)
      __builtin_amdgcn_global_load_lds(
        (const AS1 void*)(bsrc[p] + kt*64),
        (AS3 void*)(&Bs[bi][(p*512 + tid)*16]), 16, 0, 0);
  };

  const int nK = K / 32;       // 88 or 44
  stage(0,0); stage(1,1); stage(2,2);   // 12 outstanding

  const int arow0 = wr*64 + (lane & 15);
  const int brow0 = wc*128 + (lane & 15);
  const int sread = (lane >> 4) << 4;

  #pragma unroll 1
  for (int kt = 0; kt < nK; ++kt){
    if (kt < nK-2)       asm volatile("s_waitcnt vmcnt(8)\n\ts_barrier" ::: "memory");
    else if (kt == nK-2) asm volatile("s_waitcnt vmcnt(4)\n\ts_barrier" ::: "memory");
    else                 asm volatile("s_waitcnt vmcnt(0)\n\ts_barrier" ::: "memory");
    const int bi = kt & 3;
    bf16x8 a[4], bb[8];
    #pragma unroll
    for (int m=0;m<4;m++){
      const int r = arow0 + m*16;
      a[m] = *(const bf16x8*)(&As[bi][r*64 + (sread ^ (((r>>1)&3)<<4))]);
    }
    #pragma unroll
    for (int n=0;n<8;n++){
      const int r = brow0 + n*16;
      bb[n] = *(const bf16x8*)(&Bs[bi][r*64 + (sread ^ (((r>>1)&3)<<4))]);
    }
    if (kt + 3 < nK) stage((kt+3)&3, kt+3);
    #pragma unroll
    for (int m=0;m<4;m++)
      #pragma unroll
      for (int n=0;n<8;n++)
        acc[m][n] = __builtin_amdgcn_mfma_f32_16x16x32_bf16(a[m], bb[n], acc[m][n], 0,0,0);
  }

  const int colbase = nt*256 + wc*128;
  #pragma unroll
  for (int m=0;m<4;m++){
    #pragma unroll
    for (int r=0;r<4;r++){
      const int rr = wr*64 + m*16 + ((lane >> 4) << 2) + r;
      if (rr < valid){
        if (routed){
          unsigned short* orow = y_routed + (size_t)(rowbase + rr) * D_HID;
          #pragma unroll
          for (int n=0;n<8;n++){
            const int col = colbase + n*16 + (lane & 15);
            orow[col] = f2bf(acc[m][n][r]);
          }
        } else {
          float* orow = out + (size_t)(rowbase + rr) * D_HID;
          #pragma unroll
          for (int n=0;n<8;n++){
            const int col = colbase + n*16 + (lane & 15);
            orow[col] = acc[m][n][r];
          }
        }
      }
    }
  }
}

// ---------------- combine: out += w0*y[slot0] + w1*y[slot1]  (y is bf16, unweighted) ----
__global__ void combine_kernel(float* __restrict__ out, const unsigned short* __restrict__ y,
                               const int* __restrict__ token_slot,
                               const float* __restrict__ topk_w){
  const int i  = blockIdx.x * blockDim.x + threadIdx.x;   // float4 index into out
  const int t  = i >> 9;
  const int r4 = i & 511;
  const int s0 = token_slot[t*2+0];
  const int s1 = token_slot[t*2+1];
  const float w0 = topk_w[t*2+0];
  const float w1 = topk_w[t*2+1];
  const u16x4 a = ((const u16x4*)(y + (size_t)s0 * D_HID))[r4];
  const u16x4 bq = ((const u16x4*)(y + (size_t)s1 * D_HID))[r4];
  float4 o = ((float4*)out)[i];
  o.x += w0*bf2f(a[0]) + w1*bf2f(bq[0]);
  o.y += w0*bf2f(a[1]) + w1*bf2f(bq[1]);
  o.z += w0*bf2f(a[2]) + w1*bf2f(bq[2]);
  o.w += w0*bf2f(a[3]) + w1*bf2f(bq[3]);
  ((float4*)out)[i] = o;
}

extern "C" void kernel_launch(void* const* d_in, const int* in_sizes, int n_in,
                              void* d_out, int out_size, void* d_ws, size_t ws_size,
                              hipStream_t stream){
  const float* x   = (const float*)d_in[0];
  const float* Wr  = (const float*)d_in[1];
  const float* Wg  = (const float*)d_in[2];
  const float* Wu  = (const float*)d_in[3];
  const float* Wd  = (const float*)d_in[4];
  const float* Wsg = (const float*)d_in[5];
  const float* Wsu = (const float*)d_in[6];
  const float* Wsd = (const float*)d_in[7];
  float* out = (float*)d_out;
  (void)in_sizes; (void)n_in; (void)out_size; (void)ws_size;

  char* ws = (char*)d_ws;
  size_t off = 0;
  auto alloc = [&](size_t bytes)->char*{
    char* p = ws + off; off += (bytes + 255) & ~(size_t)255; return p;
  };

  unsigned short* wb       = (unsigned short*)alloc((size_t)W_TOT * 2);
  unsigned short* xb       = (unsigned short*)alloc((size_t)T_TOK * D_HID * 2);
  unsigned short* h_shared = (unsigned short*)alloc((size_t)T_TOK * FS_SH * 2);
  unsigned short* h_routed = (unsigned short*)alloc((size_t)T_TOK * 2 * F_EXP * 2);
  unsigned short* y_routed = (unsigned short*)alloc((size_t)T_TOK * 2 * D_HID * 2);
  int*   topk_e       = (int*)alloc(T_TOK*2*sizeof(int));
  float* topk_w       = (float*)alloc(T_TOK*2*sizeof(float));
  int*   cnt          = (int*)alloc(E_NUM*sizeof(int));
  int*   offs         = (int*)alloc(E_NUM*sizeof(int));
  int*   assign_token = (int*)alloc(T_TOK*2*sizeof(int));
  float* assign_w     = (float*)alloc(T_TOK*2*sizeof(float));
  int*   token_slot   = (int*)alloc(T_TOK*2*sizeof(int));
  int*   tile_rowbase = (int*)alloc(MAXT*sizeof(int));
  int*   tile_e       = (int*)alloc(MAXT*sizeof(int));
  int*   tile_valid   = (int*)alloc(MAXT*sizeof(int));
  int*   n_rt         = (int*)alloc(sizeof(int));

  prep_kernel<<<RT_BLK + WC_BLK, 256, 0, stream>>>(
      x, Wr, Wsg, Wsu, Wg, Wu, xb, wb, topk_e, topk_w);
  build_lists_kernel<<<1, 1024, 0, stream>>>(topk_e, topk_w, cnt, offs,
      assign_token, assign_w, token_slot, tile_rowbase, tile_e, tile_valid, n_rt);

  gateup_fused<<<GU_GEMM + GU_CONV, 512, 0, stream>>>(
      xb, wb, Wsd, Wd, h_shared, h_routed, tile_rowbase, tile_e, tile_valid, n_rt, assign_token);
  down_fused<<<DN_GRID, 512, 0, stream>>>(
      h_shared, h_routed, wb, out, y_routed, tile_rowbase, tile_e, tile_valid, n_rt);

  combine_kernel<<<(T_TOK*D_HID/4)/256, 256, 0, stream>>>(out, y_routed, token_slot, topk_w);
}